// Round 5
// baseline (1473.530 us; speedup 1.0000x reference)
//
#include <hip/hip_runtime.h>
#include <hip/hip_bf16.h>

// CTC loss forward: T=512, B=32, V=8000, L=100, S=2L+1=201, BLANK=0.
// Fused producer/consumer design (single kernel + tiny counter-zero kernel):
//  - blocks 0..31   = consumers: per-sample alpha recursion; poll per-(b,chunk)
//    counters, stage ready 32-row chunks into LDS, 4 states/lane in wave 0.
//  - blocks 32..16415 = producers: per (t,b) row log-sum-exp (stream 8000 floats
//    to regs, early gather-prefetch of the 101 needed classes), write log2-domain
//    logprobs to lp[b][t][RS], then RELEASE-atomicAdd cnt2[b][t/32].
//  - last consumer to finish reduces the 32 partials (same butterfly order as
//    the previous ctc_final -> bitwise-identical result) and writes d_out.
// RS=112 floats = 448 B = 7 full cache lines per row: no 64B line is written by
// two different producer blocks (avoids cross-XCD false-sharing writebacks).

#define LOG2E 1.4426950408889634f
#define LN2   0.69314718055994530942f
#define NEGS  (-1.4426950408889634e30f)   /* -1e30 scaled by log2e */
#define RS 112

__device__ __forceinline__ float lae2(float a, float b) {
    float m = fmaxf(a, b);
    float d = fminf(a, b) - m;
    return m + log2f(1.0f + exp2f(d));
}
__device__ __forceinline__ float lae3(float a, float b, float c) {
    float m = fmaxf(fmaxf(a, b), c);
    float s = exp2f(a - m) + exp2f(b - m) + exp2f(c - m);
    return m + log2f(s);
}

// -------- counter init (cnt2[512] + done[1] are poisoned 0xAA each iter) -----
__global__ __launch_bounds__(512)
void ctc_zero(int* __restrict__ cnt2, int* __restrict__ done) {
    int i = threadIdx.x;
    cnt2[i] = 0;
    if (i == 0) *done = 0;
}

// ---------------------------- fused kernel -----------------------------------
__global__ __launch_bounds__(256)
void ctc_fused(const float* __restrict__ acts, const int* __restrict__ targets,
               const int* __restrict__ act_lens, const int* __restrict__ label_lens,
               float* __restrict__ lp, float* __restrict__ partials,
               int* __restrict__ cnt2, int* __restrict__ done,
               float* __restrict__ out) {
    const int B = 32, V = 8000, L = 100;
    const int tid = threadIdx.x;

    if (blockIdx.x >= 32) {
        // ======================= producer: row LSE + gather ==================
        const int pbid = (int)blockIdx.x - 32;
        const int t = pbid >> 5, b = pbid & 31;
        __shared__ float red[8];

        const float* rowp = acts + ((size_t)t * B + b) * V;
        const float4* g = (const float4*)rowp;

        // early gather-prefetch: lines are re-used by the stream (net HBM ~0),
        // consumed only at the end -> latency fully hidden.
        float gval = 0.f;
        if (tid < 101) {
            int cls = (tid == 0) ? 0 : targets[b * L + tid - 1];
            gval = rowp[cls];
        }

        // 2000 float4 / 256 threads: threads 0..207 take 8, rest 7.
        float4 v[8];
        #pragma unroll
        for (int j = 0; j < 8; ++j) {
            int idx = tid + j * 256;
            if (j < 7 || tid < 208) v[j] = g[idx];
            else v[j] = make_float4(-3.0e38f, -3.0e38f, -3.0e38f, -3.0e38f);
        }

        float m = -3.0e38f;
        #pragma unroll
        for (int j = 0; j < 8; ++j)
            m = fmaxf(m, fmaxf(fmaxf(v[j].x, v[j].y), fmaxf(v[j].z, v[j].w)));
        #pragma unroll
        for (int o = 32; o > 0; o >>= 1) m = fmaxf(m, __shfl_xor(m, o));
        if ((tid & 63) == 0) red[tid >> 6] = m;
        __syncthreads();
        m = fmaxf(fmaxf(red[0], red[1]), fmaxf(red[2], red[3]));

        float s = 0.f;
        #pragma unroll
        for (int j = 0; j < 8; ++j) {
            s += exp2f((v[j].x - m) * LOG2E) + exp2f((v[j].y - m) * LOG2E)
               + exp2f((v[j].z - m) * LOG2E) + exp2f((v[j].w - m) * LOG2E);
        }
        #pragma unroll
        for (int o = 32; o > 0; o >>= 1) s += __shfl_xor(s, o);
        if ((tid & 63) == 0) red[4 + (tid >> 6)] = s;
        __syncthreads();
        s = red[4] + red[5] + red[6] + red[7];

        const float base = m * LOG2E + log2f(s);
        if (tid < 101)
            lp[((size_t)b * 512 + t) * RS + tid] = gval * LOG2E - base;

        __syncthreads();   // all 101 stores issued & drained before the flag
        if (tid == 0)
            __hip_atomic_fetch_add(&cnt2[b * 16 + (t >> 5)], 1,
                                   __ATOMIC_RELEASE, __HIP_MEMORY_SCOPE_AGENT);
    } else {
        // ======================= consumer: alpha recursion ===================
        const int b = (int)blockIdx.x;
        const int l = tid;                    // wave 0 (tid<64) runs recursion
        __shared__ float4 buf4[896];          // 32 rows x 112 floats = 14 KB
        __shared__ float afin[256];
        __shared__ int lastflag;

        const int* tg = targets + b * L;
        // lane l owns states 4l..4l+3; even states blank, odd = labels
        const int i1 = 2 * l;
        const int i3 = 2 * l + 1;
        const bool v1 = (4 * l + 1) <= 200;
        const bool v3 = (4 * l + 3) <= 200;
        const int q1  = (i1 < L) ? i1 : (L - 1);
        const int q1m = (i1 >= 1) ? ((i1 - 1 < L) ? i1 - 1 : (L - 1)) : 0;
        const int q3  = (i3 < L) ? i3 : (L - 1);
        const int c1 = tg[q1], c1m = tg[q1m], c3 = tg[q3];
        const bool can1 = (i1 == 0) || (c1 != c1m);
        const bool can3 = (c3 != c1);
        const int k1 = v1 ? (1 + i1) : 0;
        const int k3 = v3 ? (1 + i3) : 0;
        const int act_len = act_lens[b];

        float a0 = NEGS, a1 = NEGS, a2 = NEGS, a3 = NEGS;

        for (int c = 0; c < 16; ++c) {
            if (tid == 0) {
                // cheap relaxed spin (agent-scope -> reads coherence point)
                while (__hip_atomic_load(&cnt2[b * 16 + c], __ATOMIC_RELAXED,
                                         __HIP_MEMORY_SCOPE_AGENT) < 32)
                    __builtin_amdgcn_s_sleep(2);
                // acquire for ordering (value feeds branch -> not removable)
                while (__hip_atomic_load(&cnt2[b * 16 + c], __ATOMIC_ACQUIRE,
                                         __HIP_MEMORY_SCOPE_AGENT) < 32)
                    __builtin_amdgcn_s_sleep(1);
            }
            __syncthreads();  // tid0's acquire (L1+L2 inv, same CU) + barrier

            const float4* gsrc = (const float4*)(lp + ((size_t)b * 512 + c * 32) * RS);
            for (int i = tid; i < 896; i += 256) buf4[i] = gsrc[i];
            __syncthreads();

            if (tid < 64) {
                const float* rowbase = (const float*)buf4;
                if (c == 0 && l == 0) { a0 = rowbase[0]; a1 = rowbase[1]; }
                const int tstart = (c == 0) ? 1 : 0;
                for (int tt = tstart; tt < 32; ++tt) {
                    const float* row = rowbase + tt * RS;
                    float lpB = row[0];
                    float lq1 = v1 ? row[k1] : NEGS;
                    float lq3 = v3 ? row[k3] : NEGS;
                    float p3 = __shfl_up(a3, 1);       // alpha[4l-1] from lane l-1
                    if (l == 0) p3 = NEGS;
                    float na0 = lae2(a0, p3) + lpB;
                    float na1 = lae3(a1, a0, can1 ? p3 : NEGS) + lq1;
                    float na2 = lae2(a2, a1) + lpB;
                    float na3 = lae3(a3, a2, can3 ? a1 : NEGS) + lq3;
                    if (c * 32 + tt < act_len) { a0 = na0; a1 = na1; a2 = na2; a3 = na3; }
                }
            }
            // next iteration's top barrier protects buf4 reuse
        }

        if (tid < 64) {
            afin[4 * l + 0] = a0; afin[4 * l + 1] = a1;
            afin[4 * l + 2] = a2; afin[4 * l + 3] = a3;
        }
        __syncthreads();
        if (tid == 0) {
            int Lb = label_lens[b];
            int sl = 2 * Lb;
            float ll = lae2(afin[sl], afin[sl - 1]);   // log2 domain
            partials[b] = -ll * LN2;
            int old = __hip_atomic_fetch_add(done, 1, __ATOMIC_ACQ_REL,
                                             __HIP_MEMORY_SCOPE_AGENT);
            lastflag = (old == 31) ? 1 : 0;
        }
        __syncthreads();
        if (lastflag && tid < 64) {
            // same butterfly order as the old ctc_final -> bitwise-identical
            float vv = (tid < 32) ? partials[tid] : 0.f;
            #pragma unroll
            for (int o = 32; o > 0; o >>= 1) vv += __shfl_xor(vv, o);
            if (tid == 0) out[0] = vv * (1.0f / 32.0f);
        }
    }
}

extern "C" void kernel_launch(void* const* d_in, const int* in_sizes, int n_in,
                              void* d_out, int out_size, void* d_ws, size_t ws_size,
                              hipStream_t stream) {
    const float* acts       = (const float*)d_in[0];
    const int*   targets    = (const int*)d_in[1];
    const int*   act_lens   = (const int*)d_in[2];
    const int*   label_lens = (const int*)d_in[3];

    // ws layout (RS=112): lp [32][512][112] floats, then partials/cnt2/done
    char* w = (char*)d_ws;
    float* lp       = (float*)w;                                  // 7,340,032 B
    float* partials = (float*)(w + 7340032);                      // 128 B
    int*   cnt2     = (int*)  (w + 7340032 + 128);                // 2048 B
    int*   done     = (int*)  (w + 7340032 + 128 + 2048);         // 4 B

    ctc_zero <<<1, 512, 0, stream>>>(cnt2, done);
    ctc_fused<<<16416, 256, 0, stream>>>(acts, targets, act_lens, label_lens,
                                         lp, partials, cnt2, done, (float*)d_out);
}

// Round 6
// 816.926 us; speedup vs baseline: 1.8037x; 1.8037x over previous
//
#include <hip/hip_runtime.h>
#include <hip/hip_bf16.h>

// CTC loss forward: T=512, B=32, V=8000, L=100, S=2L+1=201, BLANK=0.
//  K1 ctc_rowlse (16384 x 256): per (t,b) row: early gather-prefetch of the
//     101 needed classes into regs (lines re-used by the stream, latency
//     hidden), stream 8000 floats HBM->regs (8 float4/thr), max + exp2-sum,
//     write log2-domain logprobs to ws lp[B][T][104]. Block 0 zeroes `done`.
//  K2 ctc_alpha (32 x 64): per-sample blocked alpha recursion, 4 states/lane,
//     one shfl_up/step, lp double-buffered in LDS; last-done block reduces the
//     32 partials (same butterfly order as the old ctc_final -> bitwise-same)
//     and writes d_out. Only 32 agent-scope release RMWs total (cheap; the
//     R5 regression came from 16384 of them: each emits an L2 writeback).

#define LOG2E 1.4426950408889634f
#define LN2   0.69314718055994530942f
#define NEGS  (-1.4426950408889634e30f)   /* -1e30 scaled by log2e */

__device__ __forceinline__ float lae2(float a, float b) {
    float m = fmaxf(a, b);
    float d = fminf(a, b) - m;
    return m + log2f(1.0f + exp2f(d));
}
__device__ __forceinline__ float lae3(float a, float b, float c) {
    float m = fmaxf(fmaxf(a, b), c);
    float s = exp2f(a - m) + exp2f(b - m) + exp2f(c - m);
    return m + log2f(s);
}

// ---------------- Kernel 1: row log-sum-exp + gather (register-resident) ----------------
__global__ __launch_bounds__(256)
void ctc_rowlse(const float* __restrict__ acts, const int* __restrict__ targets,
                float* __restrict__ lp, int* __restrict__ done) {
    const int B = 32, V = 8000, L = 100, RS = 104;
    const int bid = blockIdx.x;
    const int t = bid >> 5, b = bid & 31;
    const int tid = threadIdx.x;

    if (bid == 0 && tid == 0)   // re-arm K2's last-done counter every call
        __hip_atomic_store(done, 0, __ATOMIC_RELAXED, __HIP_MEMORY_SCOPE_AGENT);

    __shared__ float red[8];

    const float* rowp = acts + ((size_t)t * B + b) * V;
    const float4* g = (const float4*)rowp;

    // Early gather-prefetch: the 101 needed-class loads go out FIRST; they hit
    // lines the stream needs anyway (net extra HBM ~0) and are consumed last,
    // so their latency is fully hidden under the stream.
    float gval = 0.f;
    if (tid < 101) {
        int cls = (tid == 0) ? 0 : targets[b * L + tid - 1];
        gval = rowp[cls];
    }

    // 2000 float4 / 256 threads: threads 0..207 take 8, rest 7 (guard j==7).
    float4 v[8];
    #pragma unroll
    for (int j = 0; j < 8; ++j) {
        int idx = tid + j * 256;
        if (j < 7 || tid < 208) v[j] = g[idx];
        else v[j] = make_float4(-3.0e38f, -3.0e38f, -3.0e38f, -3.0e38f);
    }

    float m = -3.0e38f;
    #pragma unroll
    for (int j = 0; j < 8; ++j)
        m = fmaxf(m, fmaxf(fmaxf(v[j].x, v[j].y), fmaxf(v[j].z, v[j].w)));
    #pragma unroll
    for (int o = 32; o > 0; o >>= 1) m = fmaxf(m, __shfl_xor(m, o));
    if ((tid & 63) == 0) red[tid >> 6] = m;
    __syncthreads();
    m = fmaxf(fmaxf(red[0], red[1]), fmaxf(red[2], red[3]));

    float s = 0.f;
    #pragma unroll
    for (int j = 0; j < 8; ++j) {
        s += exp2f((v[j].x - m) * LOG2E) + exp2f((v[j].y - m) * LOG2E)
           + exp2f((v[j].z - m) * LOG2E) + exp2f((v[j].w - m) * LOG2E);
    }
    #pragma unroll
    for (int o = 32; o > 0; o >>= 1) s += __shfl_xor(s, o);
    if ((tid & 63) == 0) red[4 + (tid >> 6)] = s;
    __syncthreads();
    s = red[4] + red[5] + red[6] + red[7];

    const float base = m * LOG2E + log2f(s);   // log2(sum exp), incl. max

    if (tid < 101) {
        // lp2 = (x - logsumexp) * log2e, stored in log2 domain
        lp[((size_t)b * 512 + t) * RS + tid] = gval * LOG2E - base;
    }
}

// -------- Kernel 2: alpha recursion (1 wave / sample) + last-done reduce --------
__global__ __launch_bounds__(64)
void ctc_alpha(const float* __restrict__ lp, const int* __restrict__ targets,
               const int* __restrict__ act_lens, const int* __restrict__ label_lens,
               float* __restrict__ partials, int* __restrict__ done,
               float* __restrict__ out) {
    const int T = 512, L = 100, RS = 104, CH = 32;
    const int b = blockIdx.x;
    const int l = threadIdx.x;

    __shared__ float4 buf[2][CH * RS / 4];   // 2 x 3328 floats = 26.6 KB
    __shared__ float afin[256];
    __shared__ int lastflag;

    const int* tg = targets + b * L;

    // lane l owns states s0..s0+3; even states = blank (k=0), odd = labels
    const int s0 = 4 * l;
    const int i1 = 2 * l;        // label index of state s0+1
    const int i3 = 2 * l + 1;    // label index of state s0+3
    const bool v1 = (s0 + 1) <= 200;
    const bool v3 = (s0 + 3) <= 200;
    const int q1  = (i1 < L) ? i1 : (L - 1);
    const int q1m = (i1 >= 1) ? ((i1 - 1 < L) ? i1 - 1 : (L - 1)) : 0;
    const int q3  = (i3 < L) ? i3 : (L - 1);
    const int c1 = tg[q1], c1m = tg[q1m], c3 = tg[q3];
    const bool can1 = (i1 == 0) || (c1 != c1m);
    const bool can3 = (c3 != c1);
    const int k1 = v1 ? (1 + i1) : 0;
    const int k3 = v3 ? (1 + i3) : 0;
    const int act_len = act_lens[b];

    const float4* gsrc = (const float4*)(lp + (size_t)b * T * RS);

    // stage chunk 0
    float4 stg[13];
    #pragma unroll
    for (int i = 0; i < 13; ++i) stg[i] = gsrc[i * 64 + l];
    #pragma unroll
    for (int i = 0; i < 13; ++i) buf[0][i * 64 + l] = stg[i];
    __syncthreads();

    float a0 = NEGS, a1 = NEGS, a2 = NEGS, a3 = NEGS;
    {
        const float* row0 = (const float*)&buf[0][0];
        if (l == 0) { a0 = row0[0]; a1 = row0[1]; }
    }

    int gt = 1;
    for (int c = 0; c < 16; ++c) {
        if (c < 15) {   // issue next-chunk loads early (hide under compute)
            const float4* gn = gsrc + (size_t)(c + 1) * (CH * RS / 4);
            #pragma unroll
            for (int i = 0; i < 13; ++i) stg[i] = gn[i * 64 + l];
        }
        const float* rowbase = (const float*)&buf[c & 1][0];
        const int tstart = (c == 0) ? 1 : 0;
        for (int tt = tstart; tt < CH; ++tt, ++gt) {
            const float* row = rowbase + tt * RS;
            float lpB = row[0];
            float lq1 = v1 ? row[k1] : NEGS;
            float lq3 = v3 ? row[k3] : NEGS;
            float p3 = __shfl_up(a3, 1);           // alpha[s0-1] from lane l-1
            if (l == 0) p3 = NEGS;
            float na0 = lae2(a0, p3) + lpB;
            float na1 = lae3(a1, a0, can1 ? p3 : NEGS) + lq1;
            float na2 = lae2(a2, a1) + lpB;
            float na3 = lae3(a3, a2, can3 ? a1 : NEGS) + lq3;
            if (gt < act_len) { a0 = na0; a1 = na1; a2 = na2; a3 = na3; }
        }
        if (c < 15) {   // commit staged chunk, then make visible
            float4* dst = &buf[(c + 1) & 1][0];
            #pragma unroll
            for (int i = 0; i < 13; ++i) dst[i * 64 + l] = stg[i];
            __syncthreads();
        }
    }

    afin[4 * l + 0] = a0; afin[4 * l + 1] = a1;
    afin[4 * l + 2] = a2; afin[4 * l + 3] = a3;
    __syncthreads();
    if (l == 0) {
        int Lb = label_lens[b];
        int sl = 2 * Lb;
        float ll = lae2(afin[sl], afin[sl - 1]);   // log2 domain
        float pb = -ll * LN2;                      // back to natural log
        __hip_atomic_store(&partials[b], pb, __ATOMIC_RELAXED,
                           __HIP_MEMORY_SCOPE_AGENT);
        // ACQ_REL RMW: release makes the partials store visible device-wide
        // before the increment; acquire lets the winner read all 32. Only 32
        // of these in total -> L2 writeback cost is negligible.
        int old = __hip_atomic_fetch_add(done, 1, __ATOMIC_ACQ_REL,
                                         __HIP_MEMORY_SCOPE_AGENT);
        lastflag = (old == 31) ? 1 : 0;
    }
    __syncthreads();
    if (lastflag) {
        // same butterfly order as the previous ctc_final -> bitwise-identical
        float vv = (l < 32) ? __hip_atomic_load(&partials[l], __ATOMIC_RELAXED,
                                                __HIP_MEMORY_SCOPE_AGENT)
                            : 0.f;
        #pragma unroll
        for (int o = 32; o > 0; o >>= 1) vv += __shfl_xor(vv, o);
        if (l == 0) out[0] = vv * (1.0f / 32.0f);
    }
}

extern "C" void kernel_launch(void* const* d_in, const int* in_sizes, int n_in,
                              void* d_out, int out_size, void* d_ws, size_t ws_size,
                              hipStream_t stream) {
    const float* acts       = (const float*)d_in[0];
    const int*   targets    = (const int*)d_in[1];
    const int*   act_lens   = (const int*)d_in[2];
    const int*   label_lens = (const int*)d_in[3];

    // ws layout: lp [32][512][104] f32 (6,815,744 B), partials[32], done[1]
    char* w = (char*)d_ws;
    float* lp       = (float*)w;
    float* partials = (float*)(w + 6815744);
    int*   done     = (int*)  (w + 6815744 + 128);

    ctc_rowlse<<<16384, 256, 0, stream>>>(acts, targets, lp, done);
    ctc_alpha <<<32, 64, 0, stream>>>(lp, targets, act_lens, label_lens,
                                      partials, done, (float*)d_out);
}